// Round 14
// baseline (130.318 us; speedup 1.0000x reference)
//
#include <hip/hip_runtime.h>
#include <math.h>

// GCN 2-layer forward — atomic-free radix CSR build + MFMA gemm1
//   + fused sort+gather1 (writes sorted CSR) + copy+gather2 (no re-sort).
// out = log_softmax( A @ relu( A @ (x@W1) + b1 ) @ W2 + b2 )
// A = sym-normalized adjacency with self-loops keyed on edge_index[0].
// isq pre-scaling: h1s = isq*(x@W1); r1s = isq*relu(isq*(h1s[r]+Σ h1s[col]) + b1)
// Self-loop: h1s[r] ALREADY carries isq[r] — init acc = h1s[r], NO isq² factor.
// h1/r1 stored fp16 (32 B row = one cache sector per edge gather).

#define DF 512
#define H1F 16
#define BROWS 256
#define PA_VPT 16
#define PA_BATCH 4096
#define A2_CAP 10240   // max edges per bucket (mean 8184, sd ~90; guard at +22σ)

typedef short bf16x8 __attribute__((ext_vector_type(8)));
typedef float f32x4 __attribute__((ext_vector_type(4)));
typedef _Float16 half8 __attribute__((ext_vector_type(8)));
typedef unsigned int u32x4 __attribute__((ext_vector_type(4)));

static __device__ __forceinline__ short bf16_rne(float f) {
    unsigned int u = __builtin_bit_cast(unsigned int, f);
    unsigned int r = (u + 0x7FFFu + ((u >> 16) & 1u)) >> 16;
    return (short)r;
}
static __device__ __forceinline__ unsigned int cvt_pk_bf16(float lo, float hi) {
    unsigned int r;
    asm("v_cvt_pk_bf16_f32 %0, %1, %2" : "=v"(r) : "v"(lo), "v"(hi));
    return r;
}

// ---- pass 1: per-block bucket histogram (lane-consecutive int4 loads) ---
__global__ __launch_bounds__(256) void k_hist(const int* __restrict__ rowi,
                                              unsigned int* __restrict__ ghist,
                                              int E, int nbkt, int nblkp) {
    __shared__ unsigned int hist[512];
    int t = threadIdx.x;
    hist[t] = 0u; hist[t + 256] = 0u;
    __syncthreads();
    int base = blockIdx.x * PA_BATCH;
    int ne = E - base; if (ne > PA_BATCH) ne = PA_BATCH;
    if (ne == PA_BATCH) {
        const int4* p4 = (const int4*)(rowi + base);
#pragma unroll
        for (int j = 0; j < 4; ++j) {
            int4 v = p4[j * 256 + t];
            atomicAdd(&hist[(unsigned int)v.x >> 8], 1u);
            atomicAdd(&hist[(unsigned int)v.y >> 8], 1u);
            atomicAdd(&hist[(unsigned int)v.z >> 8], 1u);
            atomicAdd(&hist[(unsigned int)v.w >> 8], 1u);
        }
    } else {
        for (int j = t; j < ne; j += 256)
            atomicAdd(&hist[(unsigned int)rowi[base + j] >> 8], 1u);
    }
    __syncthreads();
    for (int b = t; b < nbkt; b += 256)
        ghist[(size_t)b * nblkp + blockIdx.x] = hist[b];
}

// ---- pass 2: per-bucket exclusive scan over blocks → bases + totals -----
__global__ __launch_bounds__(256) void k_colscan(const unsigned int* __restrict__ ghist,
                                                 unsigned int* __restrict__ gbase,
                                                 unsigned int* __restrict__ btot,
                                                 int nblk, int nblkp) {
    __shared__ unsigned int s[256];
    int t = threadIdx.x, b = blockIdx.x;
    unsigned int carry = 0u;
    int nch = (nblk + 255) / 256;
    for (int ch = 0; ch < nch; ++ch) {
        int idx = ch * 256 + t;
        unsigned int v = (idx < nblk) ? ghist[(size_t)b * nblkp + idx] : 0u;
        s[t] = v;
        __syncthreads();
        for (int off = 1; off < 256; off <<= 1) {
            unsigned int u = (t >= off) ? s[t - off] : 0u;
            __syncthreads();
            s[t] += u;
            __syncthreads();
        }
        if (idx < nblk) gbase[(size_t)b * nblkp + idx] = carry + s[t] - v;
        unsigned int tot = s[255];
        __syncthreads();
        carry += tot;
    }
    if (t == 0) btot[b] = carry;
}

// ---- pass 3: deterministic multisplit scatter (no global atomics) -------
__global__ __launch_bounds__(256) void k_scatter(const int* __restrict__ rowi,
                                                 const int* __restrict__ coli,
                                                 const unsigned int* __restrict__ gbase,
                                                 const unsigned int* __restrict__ btot,
                                                 unsigned int* __restrict__ pairs,
                                                 int E, int nbkt, int nblkp) {
    __shared__ unsigned int hist[512];
    __shared__ unsigned int sA[512];
    __shared__ unsigned int sB[512];
    __shared__ unsigned int gb[512];
    __shared__ unsigned int reorder[PA_BATCH];
    __shared__ unsigned short bid[PA_BATCH];
    int t = threadIdx.x;
    int base = blockIdx.x * PA_BATCH;
    int ne = E - base; if (ne > PA_BATCH) ne = PA_BATCH;

    // --- scan btot → exclusive bpref, + per-block gbase → gb ---
    unsigned int b0 = (t < nbkt) ? btot[t] : 0u;
    unsigned int b1v = (t + 256 < nbkt) ? btot[t + 256] : 0u;
    sA[t] = b0; sA[t + 256] = b1v;
    __syncthreads();
    {
        unsigned int* src = sA; unsigned int* dst = sB;
        for (int off = 1; off < 512; off <<= 1) {
            unsigned int v0 = src[t] + ((t >= off) ? src[t - off] : 0u);
            unsigned int v1 = src[t + 256] + src[t + 256 - off];
            dst[t] = v0; dst[t + 256] = v1;
            __syncthreads();
            unsigned int* tmp = src; src = dst; dst = tmp;
        }
        gb[t] = src[t] - b0;
        gb[t + 256] = src[t + 256] - b1v;
        if (t < nbkt) gb[t] += gbase[(size_t)t * nblkp + blockIdx.x];
        if (t + 256 < nbkt) gb[t + 256] += gbase[(size_t)(t + 256) * nblkp + blockIdx.x];
    }

    hist[t] = 0u; hist[t + 256] = 0u;
    __syncthreads();

    unsigned int pk[PA_VPT]; unsigned int bk[PA_VPT]; unsigned int rk[PA_VPT];
    if (ne == PA_BATCH) {
        const int4* r4 = (const int4*)(rowi + base);
        const int4* c4 = (const int4*)(coli + base);
#pragma unroll
        for (int jj = 0; jj < 4; ++jj) {
            int4 rv = r4[jj * 256 + t];
            int4 cv = c4[jj * 256 + t];
            int rr[4] = {rv.x, rv.y, rv.z, rv.w};
            int cc[4] = {cv.x, cv.y, cv.z, cv.w};
#pragma unroll
            for (int q = 0; q < 4; ++q) {
                int j = jj * 4 + q;
                unsigned int b = (unsigned int)rr[q] >> 8;
                pk[j] = ((unsigned int)(rr[q] & (BROWS - 1)) << 17) | (unsigned int)cc[q];
                bk[j] = b;
                rk[j] = atomicAdd(&hist[b], 1u);
            }
        }
    } else {
#pragma unroll
        for (int j = 0; j < PA_VPT; ++j) {
            int idx = j * 256 + t;
            if (idx < ne) {
                int r = rowi[base + idx];
                int c = coli[base + idx];
                unsigned int b = (unsigned int)r >> 8;
                pk[j] = ((unsigned int)(r & (BROWS - 1)) << 17) | (unsigned int)c;
                bk[j] = b;
                rk[j] = atomicAdd(&hist[b], 1u);
            } else bk[j] = 0xFFFFFFFFu;
        }
    }
    __syncthreads();

    sA[t] = hist[t]; sA[t + 256] = hist[t + 256];
    __syncthreads();
    unsigned int* src = sA; unsigned int* dst = sB;
    for (int off = 1; off < 512; off <<= 1) {
        unsigned int v0 = src[t] + ((t >= off) ? src[t - off] : 0u);
        unsigned int v1 = src[t + 256] + src[t + 256 - off];
        dst[t] = v0; dst[t + 256] = v1;
        __syncthreads();
        unsigned int* tmp = src; src = dst; dst = tmp;
    }

#pragma unroll
    for (int j = 0; j < PA_VPT; ++j) {
        if ((ne == PA_BATCH) || (bk[j] != 0xFFFFFFFFu)) {
            unsigned int b = bk[j];
            unsigned int slot = src[b] - hist[b] + rk[j];
            reorder[slot] = pk[j];
            bid[slot] = (unsigned short)b;
        }
    }
    __syncthreads();

    for (int s = t; s < ne; s += 256) {
        unsigned int b = bid[s];
        unsigned int off = src[b] - hist[b];
        pairs[gb[b] + ((unsigned int)s - off)] = reorder[s];
    }
}

// ---- pass 4a: per-bucket counting → rowloc/isq/bpref --------------------
__global__ __launch_bounds__(512) void k_count(const unsigned int* __restrict__ pairs,
                                               const unsigned int* __restrict__ btot,
                                               unsigned int* __restrict__ bpref_g,
                                               unsigned int* __restrict__ rowloc,
                                               float* __restrict__ isq, int n, int nbkt) {
    __shared__ unsigned int bsc[512];
    __shared__ unsigned int rcnt[256];
    __shared__ unsigned int ssc[256];
    int t = threadIdx.x;
    int b = blockIdx.x;
    int r0 = b * 256;

    bsc[t] = (t < nbkt) ? btot[t] : 0u;
    __syncthreads();
    for (int off = 1; off < 512; off <<= 1) {
        unsigned int u = (t >= off) ? bsc[t - off] : 0u;
        __syncthreads();
        bsc[t] += u;
        __syncthreads();
    }
    unsigned int bp = (b > 0) ? bsc[b - 1] : 0u;
    unsigned int cnt = btot[b];
    if (t == 0) bpref_g[b] = bp;
    if (cnt > A2_CAP) cnt = A2_CAP;

    if (t < 256) rcnt[t] = 0u;
    __syncthreads();
    {
        unsigned int nv4 = cnt >> 2;
        const u32x4* p4 = (const u32x4*)(pairs + bp);
        for (unsigned int i = t; i < nv4; i += 512) {
            u32x4 v = p4[i];
            atomicAdd(&rcnt[v[0] >> 17], 1u);
            atomicAdd(&rcnt[v[1] >> 17], 1u);
            atomicAdd(&rcnt[v[2] >> 17], 1u);
            atomicAdd(&rcnt[v[3] >> 17], 1u);
        }
        for (unsigned int i = (nv4 << 2) + t; i < cnt; i += 512)
            atomicAdd(&rcnt[pairs[bp + i] >> 17], 1u);
    }
    __syncthreads();
    unsigned int d = 0;
    if (t < 256) { d = rcnt[t]; ssc[t] = d; }
    __syncthreads();
    for (int off = 1; off < 256; off <<= 1) {
        unsigned int u = 0;
        if (t < 256 && t >= off) u = ssc[t - off];
        __syncthreads();
        if (t < 256) ssc[t] += u;
        __syncthreads();
    }
    if (t < 256 && r0 + t < n) {
        rowloc[r0 + t] = ssc[t] - d;
        isq[r0 + t] = rsqrtf((float)(d + 1u));
    }
}

// ---- layer 1 GEMM via MFMA: h1h = fp16(isq * (x @ W1)) ------------------
__global__ __launch_bounds__(256) void k_gemm1(const float* __restrict__ x,
                                               const float* __restrict__ W1,
                                               const float* __restrict__ isq,
                                               _Float16* __restrict__ h1h,
                                               int n, int ntile, int tstride) {
    int wave = threadIdx.x >> 6;
    int lane = threadIdx.x & 63;
    int g = lane >> 4;
    int m = lane & 15;

    bf16x8 wf[16];
#pragma unroll
    for (int s = 0; s < 16; ++s) {
#pragma unroll
        for (int j = 0; j < 8; ++j) {
            int k = s * 32 + g * 8 + j;
            wf[s][j] = bf16_rne(W1[k * H1F + m]);
        }
    }

    for (int tile = blockIdx.x * 4 + wave; tile < ntile; tile += tstride) {
        long r0 = (long)tile * 16;
        const float* xrow = x + (r0 + m) * DF;
        f32x4 acc = {0.0f, 0.0f, 0.0f, 0.0f};
#pragma unroll
        for (int s = 0; s < 16; ++s) {
            const float4* p = (const float4*)(xrow + s * 32 + g * 8);
            float4 a0 = p[0];
            float4 a1 = p[1];
            u32x4 aw;
            aw[0] = cvt_pk_bf16(a0.x, a0.y);
            aw[1] = cvt_pk_bf16(a0.z, a0.w);
            aw[2] = cvt_pk_bf16(a1.x, a1.y);
            aw[3] = cvt_pk_bf16(a1.z, a1.w);
            bf16x8 af = __builtin_bit_cast(bf16x8, aw);
            acc = __builtin_amdgcn_mfma_f32_16x16x32_bf16(af, wf[s], acc, 0, 0, 0);
        }
#pragma unroll
        for (int j = 0; j < 4; ++j) {
            long rr = r0 + g * 4 + j;
            h1h[rr * H1F + m] = (_Float16)(isq[rr] * acc[j]);
        }
    }
}

// ---- pass 4b FUSED: per-bucket counting sort (LDS CSR) + gather1 --------
// Writes the sorted CSR back so gather2 can skip its sort (copy-load only).
__global__ __launch_bounds__(1024) void k_sortg1(unsigned int* __restrict__ pairs,
                                                 const unsigned int* __restrict__ btot,
                                                 const unsigned int* __restrict__ bpref_g,
                                                 const unsigned int* __restrict__ rowloc,
                                                 const float* __restrict__ isq,
                                                 const _Float16* __restrict__ h1h,
                                                 const float* __restrict__ b1,
                                                 _Float16* __restrict__ r1h, int n) {
    __shared__ unsigned int sorted[A2_CAP];   // 40 KB
    __shared__ unsigned int rloc[256];
    __shared__ unsigned int rcur[256];
    int t = threadIdx.x;
    int b = blockIdx.x;
    int r0 = b * 256;
    unsigned int bp = bpref_g[b];
    unsigned int cnt = btot[b];
    if (cnt > A2_CAP) cnt = A2_CAP;

    if (t < 256) {
        rloc[t] = (r0 + t < n) ? rowloc[r0 + t] : 0u;
        rcur[t] = 0u;
    }
    __syncthreads();
    {
        unsigned int nv4 = cnt >> 2;
        const u32x4* p4 = (const u32x4*)(pairs + bp);
        for (unsigned int i = t; i < nv4; i += 1024) {
            u32x4 v = p4[i];
#pragma unroll
            for (int q = 0; q < 4; ++q) {
                unsigned int lr = v[q] >> 17;
                unsigned int rk = atomicAdd(&rcur[lr], 1u);
                sorted[rloc[lr] + rk] = v[q] & 0x1FFFFu;
            }
        }
        for (unsigned int i = (nv4 << 2) + t; i < cnt; i += 1024) {
            unsigned int p = pairs[bp + i];
            unsigned int lr = p >> 17;
            unsigned int rk = atomicAdd(&rcur[lr], 1u);
            sorted[rloc[lr] + rk] = p & 0x1FFFFu;
        }
    }
    __syncthreads();
    // coalesced write-back: pairs becomes the sorted col list for gather2
    for (unsigned int i = t; i < cnt; i += 1024) pairs[bp + i] = sorted[i];

    // ---- gather1 phase: 4 lanes/row, CSR from LDS, 4-deep MLP ----
    int lr = t >> 2;
    int r = r0 + lr;
    if (r >= n) return;
    int hf = t & 1, sg = (t >> 1) & 1;
    unsigned int start = rloc[lr];
    unsigned int cntr = rcur[lr];     // row degree, free from the sort
    float s = isq[r];
    const half8* hb = (const half8*)h1h;
    float acc[8];
    if (sg == 0) {
        half8 me = hb[(size_t)r * 2 + hf];
#pragma unroll
        for (int i = 0; i < 8; ++i) acc[i] = (float)me[i];   // self-loop term
    } else {
#pragma unroll
        for (int i = 0; i < 8; ++i) acc[i] = 0.0f;
    }
    unsigned int k = sg;
    for (; k + 6 < cntr; k += 8) {
        unsigned int c0 = sorted[start + k];
        unsigned int c1 = sorted[start + k + 2];
        unsigned int c2 = sorted[start + k + 4];
        unsigned int c3 = sorted[start + k + 6];
        half8 v0 = hb[(size_t)c0 * 2 + hf];
        half8 v1 = hb[(size_t)c1 * 2 + hf];
        half8 v2 = hb[(size_t)c2 * 2 + hf];
        half8 v3 = hb[(size_t)c3 * 2 + hf];
#pragma unroll
        for (int i = 0; i < 8; ++i)
            acc[i] += ((float)v0[i] + (float)v1[i]) + ((float)v2[i] + (float)v3[i]);
    }
    for (; k < cntr; k += 2) {
        unsigned int c0 = sorted[start + k];
        half8 v0 = hb[(size_t)c0 * 2 + hf];
#pragma unroll
        for (int i = 0; i < 8; ++i) acc[i] += (float)v0[i];
    }
#pragma unroll
    for (int i = 0; i < 8; ++i) acc[i] += __shfl_xor(acc[i], 2);
    if (sg == 0) {
        const float* b1p = b1 + hf * 8;
        half8 o;
#pragma unroll
        for (int i = 0; i < 8; ++i)
            o[i] = (_Float16)(s * fmaxf(fmaf(s, acc[i], b1p[i]), 0.0f));
        ((half8*)r1h)[(size_t)r * 2 + hf] = o;
    }
}

// ---- pass 4c: coalesced copy-load of sorted CSR + gather2
//               + @W2 + b2 + log_softmax (no re-sort) ---------------------
__global__ __launch_bounds__(1024) void k_sortg2(const unsigned int* __restrict__ pairs,
                                                 const unsigned int* __restrict__ btot,
                                                 const unsigned int* __restrict__ bpref_g,
                                                 const unsigned int* __restrict__ rowloc,
                                                 const float* __restrict__ isq,
                                                 const _Float16* __restrict__ r1h,
                                                 const float* __restrict__ W2,
                                                 const float* __restrict__ b2,
                                                 float* __restrict__ out, int n) {
    __shared__ unsigned int sorted[A2_CAP];   // 40 KB
    __shared__ unsigned int rloc[257];
    int t = threadIdx.x;
    int b = blockIdx.x;
    int r0 = b * 256;
    unsigned int bp = bpref_g[b];
    unsigned int cnt = btot[b];
    if (cnt > A2_CAP) cnt = A2_CAP;

    if (t < 256) rloc[t] = (r0 + t < n) ? rowloc[r0 + t] : cnt;  // sentinel=cnt
    if (t == 0) rloc[256] = cnt;
    __syncthreads();
    {
        unsigned int nv4 = cnt >> 2;
        const u32x4* p4 = (const u32x4*)(pairs + bp);
        for (unsigned int i = t; i < nv4; i += 1024) {
            u32x4 v = p4[i];
            unsigned int j = i << 2;
            sorted[j + 0] = v[0];
            sorted[j + 1] = v[1];
            sorted[j + 2] = v[2];
            sorted[j + 3] = v[3];
        }
        for (unsigned int i = (nv4 << 2) + t; i < cnt; i += 1024)
            sorted[i] = pairs[bp + i];
    }
    __syncthreads();

    // ---- gather2 phase: 4 lanes/row, CSR from LDS, 4-deep MLP ----
    int lr = t >> 2;
    int r = r0 + lr;
    if (r >= n) return;
    int hf = t & 1, sg = (t >> 1) & 1;
    unsigned int start = rloc[lr];
    unsigned int cntr = rloc[lr + 1] - start;   // degree from scan diffs
    float s = isq[r];
    const half8* hb = (const half8*)r1h;
    float acc[8];
    if (sg == 0) {
        half8 me = hb[(size_t)r * 2 + hf];
#pragma unroll
        for (int i = 0; i < 8; ++i) acc[i] = (float)me[i];   // self-loop term
    } else {
#pragma unroll
        for (int i = 0; i < 8; ++i) acc[i] = 0.0f;
    }
    unsigned int k = sg;
    for (; k + 6 < cntr; k += 8) {
        unsigned int c0 = sorted[start + k];
        unsigned int c1 = sorted[start + k + 2];
        unsigned int c2 = sorted[start + k + 4];
        unsigned int c3 = sorted[start + k + 6];
        half8 v0 = hb[(size_t)c0 * 2 + hf];
        half8 v1 = hb[(size_t)c1 * 2 + hf];
        half8 v2 = hb[(size_t)c2 * 2 + hf];
        half8 v3 = hb[(size_t)c3 * 2 + hf];
#pragma unroll
        for (int i = 0; i < 8; ++i)
            acc[i] += ((float)v0[i] + (float)v1[i]) + ((float)v2[i] + (float)v3[i]);
    }
    for (; k < cntr; k += 2) {
        unsigned int c0 = sorted[start + k];
        half8 v0 = hb[(size_t)c0 * 2 + hf];
#pragma unroll
        for (int i = 0; i < 8; ++i) acc[i] += (float)v0[i];
    }
#pragma unroll
    for (int i = 0; i < 8; ++i) acc[i] += __shfl_xor(acc[i], 2);
    int f0 = hf * 8;
    float o0 = 0.0f, o1 = 0.0f;
#pragma unroll
    for (int i = 0; i < 8; ++i) {
        o0 = fmaf(acc[i], W2[(f0 + i) * 2 + 0], o0);
        o1 = fmaf(acc[i], W2[(f0 + i) * 2 + 1], o1);
    }
    o0 += __shfl_xor(o0, 1);
    o1 += __shfl_xor(o1, 1);
    if ((t & 3) == 0) {
        float a = fmaf(s, o0, b2[0]);
        float bb = fmaf(s, o1, b2[1]);
        float m = fmaxf(a, bb);
        float lse = m + logf(expf(a - m) + expf(bb - m));
        out[(size_t)r * 2 + 0] = a - lse;
        out[(size_t)r * 2 + 1] = bb - lse;
    }
}

extern "C" void kernel_launch(void* const* d_in, const int* in_sizes, int n_in,
                              void* d_out, int out_size, void* d_ws, size_t ws_size,
                              hipStream_t stream) {
    const float* x  = (const float*)d_in[0];
    const int*   ei = (const int*)d_in[1];
    const float* W1 = (const float*)d_in[2];
    const float* b1 = (const float*)d_in[3];
    const float* W2 = (const float*)d_in[4];
    const float* b2 = (const float*)d_in[5];

    int n = in_sizes[0] / DF;   // 100000
    int E = in_sizes[1] / 2;    // 3200000
    const int* rowi = ei;
    const int* coli = ei + E;

    int NBKT = (n + BROWS - 1) / BROWS;          // 391
    int NBLK = (E + PA_BATCH - 1) / PA_BATCH;    // 782
    int NBLKP = NBLK + 2;                        // padded leading dim

    char* base = (char*)d_ws;
    float*        isq    = (float*)base;        base += (size_t)n * 4;
    unsigned int* rowloc = (unsigned int*)base; base += (size_t)n * 4;
    unsigned int* btot   = (unsigned int*)base; base += 512 * 4;
    unsigned int* bpref  = (unsigned int*)base; base += 512 * 4;
    unsigned int* ghist  = (unsigned int*)base; base += (size_t)NBKT * NBLKP * 4;
    unsigned int* gbase  = (unsigned int*)base; base += (size_t)NBKT * NBLKP * 4;
    _Float16*     h1h    = (_Float16*)base;     base += (size_t)n * H1F * 2;
    _Float16*     r1h    = (_Float16*)base;     base += (size_t)n * H1F * 2;
    unsigned int* pairs  = (unsigned int*)base; base += (size_t)E * 4;
    float*        out    = (float*)d_out;

    k_hist<<<NBLK, 256, 0, stream>>>(rowi, ghist, E, NBKT, NBLKP);
    k_colscan<<<NBKT, 256, 0, stream>>>(ghist, gbase, btot, NBLK, NBLKP);
    k_scatter<<<NBLK, 256, 0, stream>>>(rowi, coli, gbase, btot, pairs, E, NBKT, NBLKP);
    k_count<<<NBKT, 512, 0, stream>>>(pairs, btot, bpref, rowloc, isq, n, NBKT);
    {
        int ntile = (n + 15) / 16;                 // 6250
        int ngrid = 782;                           // ~2 tiles per wave
        k_gemm1<<<ngrid, 256, 0, stream>>>(x, W1, isq, h1h, n, ntile, ngrid * 4);
    }
    k_sortg1<<<NBKT, 1024, 0, stream>>>(pairs, btot, bpref, rowloc, isq, h1h, b1, r1h, n);
    k_sortg2<<<NBKT, 1024, 0, stream>>>(pairs, btot, bpref, rowloc, isq, r1h, W2, b2, out, n);
}

// Round 15
// 123.873 us; speedup vs baseline: 1.0520x; 1.0520x over previous
//
#include <hip/hip_runtime.h>
#include <math.h>

// GCN 2-layer forward — atomic-free radix CSR build + MFMA gemm1
//   + fused per-bucket sort+gather for BOTH layers (CSR never re-written).
// out = log_softmax( A @ relu( A @ (x@W1) + b1 ) @ W2 + b2 )
// A = sym-normalized adjacency with self-loops keyed on edge_index[0].
// isq pre-scaling: h1s = isq*(x@W1); r1s = isq*relu(isq*(h1s[r]+Σ h1s[col]) + b1)
// Self-loop: h1s[r] ALREADY carries isq[r] — init acc = h1s[r], NO isq² factor.
// h1/r1 stored fp16 (32 B row = one cache sector per edge gather).
// NOTE (r14 lesson): re-sorting pairs from L2 in EACH gather kernel beats
// writing the sorted CSR back to global (write-back regressed +4.6 µs).

#define DF 512
#define H1F 16
#define BROWS 256
#define PA_VPT 16
#define PA_BATCH 4096
#define A2_CAP 10240   // max edges per bucket (mean 8184, sd ~90; guard at +22σ)

typedef short bf16x8 __attribute__((ext_vector_type(8)));
typedef float f32x4 __attribute__((ext_vector_type(4)));
typedef _Float16 half8 __attribute__((ext_vector_type(8)));
typedef unsigned int u32x4 __attribute__((ext_vector_type(4)));

static __device__ __forceinline__ short bf16_rne(float f) {
    unsigned int u = __builtin_bit_cast(unsigned int, f);
    unsigned int r = (u + 0x7FFFu + ((u >> 16) & 1u)) >> 16;
    return (short)r;
}
static __device__ __forceinline__ unsigned int cvt_pk_bf16(float lo, float hi) {
    unsigned int r;
    asm("v_cvt_pk_bf16_f32 %0, %1, %2" : "=v"(r) : "v"(lo), "v"(hi));
    return r;
}

// ---- pass 1: per-block bucket histogram (lane-consecutive int4 loads) ---
__global__ __launch_bounds__(256) void k_hist(const int* __restrict__ rowi,
                                              unsigned int* __restrict__ ghist,
                                              int E, int nbkt, int nblkp) {
    __shared__ unsigned int hist[512];
    int t = threadIdx.x;
    hist[t] = 0u; hist[t + 256] = 0u;
    __syncthreads();
    int base = blockIdx.x * PA_BATCH;
    int ne = E - base; if (ne > PA_BATCH) ne = PA_BATCH;
    if (ne == PA_BATCH) {
        const int4* p4 = (const int4*)(rowi + base);
#pragma unroll
        for (int j = 0; j < 4; ++j) {
            int4 v = p4[j * 256 + t];
            atomicAdd(&hist[(unsigned int)v.x >> 8], 1u);
            atomicAdd(&hist[(unsigned int)v.y >> 8], 1u);
            atomicAdd(&hist[(unsigned int)v.z >> 8], 1u);
            atomicAdd(&hist[(unsigned int)v.w >> 8], 1u);
        }
    } else {
        for (int j = t; j < ne; j += 256)
            atomicAdd(&hist[(unsigned int)rowi[base + j] >> 8], 1u);
    }
    __syncthreads();
    for (int b = t; b < nbkt; b += 256)
        ghist[(size_t)b * nblkp + blockIdx.x] = hist[b];
}

// ---- pass 2: per-bucket exclusive scan over blocks → bases + totals -----
__global__ __launch_bounds__(256) void k_colscan(const unsigned int* __restrict__ ghist,
                                                 unsigned int* __restrict__ gbase,
                                                 unsigned int* __restrict__ btot,
                                                 int nblk, int nblkp) {
    __shared__ unsigned int s[256];
    int t = threadIdx.x, b = blockIdx.x;
    unsigned int carry = 0u;
    int nch = (nblk + 255) / 256;
    for (int ch = 0; ch < nch; ++ch) {
        int idx = ch * 256 + t;
        unsigned int v = (idx < nblk) ? ghist[(size_t)b * nblkp + idx] : 0u;
        s[t] = v;
        __syncthreads();
        for (int off = 1; off < 256; off <<= 1) {
            unsigned int u = (t >= off) ? s[t - off] : 0u;
            __syncthreads();
            s[t] += u;
            __syncthreads();
        }
        if (idx < nblk) gbase[(size_t)b * nblkp + idx] = carry + s[t] - v;
        unsigned int tot = s[255];
        __syncthreads();
        carry += tot;
    }
    if (t == 0) btot[b] = carry;
}

// ---- pass 3: deterministic multisplit scatter (no global atomics) -------
__global__ __launch_bounds__(256) void k_scatter(const int* __restrict__ rowi,
                                                 const int* __restrict__ coli,
                                                 const unsigned int* __restrict__ gbase,
                                                 const unsigned int* __restrict__ btot,
                                                 unsigned int* __restrict__ pairs,
                                                 int E, int nbkt, int nblkp) {
    __shared__ unsigned int hist[512];
    __shared__ unsigned int sA[512];
    __shared__ unsigned int sB[512];
    __shared__ unsigned int gb[512];
    __shared__ unsigned int reorder[PA_BATCH];
    __shared__ unsigned short bid[PA_BATCH];
    int t = threadIdx.x;
    int base = blockIdx.x * PA_BATCH;
    int ne = E - base; if (ne > PA_BATCH) ne = PA_BATCH;

    // --- scan btot → exclusive bpref, + per-block gbase → gb ---
    unsigned int b0 = (t < nbkt) ? btot[t] : 0u;
    unsigned int b1v = (t + 256 < nbkt) ? btot[t + 256] : 0u;
    sA[t] = b0; sA[t + 256] = b1v;
    __syncthreads();
    {
        unsigned int* src = sA; unsigned int* dst = sB;
        for (int off = 1; off < 512; off <<= 1) {
            unsigned int v0 = src[t] + ((t >= off) ? src[t - off] : 0u);
            unsigned int v1 = src[t + 256] + src[t + 256 - off];
            dst[t] = v0; dst[t + 256] = v1;
            __syncthreads();
            unsigned int* tmp = src; src = dst; dst = tmp;
        }
        gb[t] = src[t] - b0;
        gb[t + 256] = src[t + 256] - b1v;
        if (t < nbkt) gb[t] += gbase[(size_t)t * nblkp + blockIdx.x];
        if (t + 256 < nbkt) gb[t + 256] += gbase[(size_t)(t + 256) * nblkp + blockIdx.x];
    }

    hist[t] = 0u; hist[t + 256] = 0u;
    __syncthreads();

    unsigned int pk[PA_VPT]; unsigned int bk[PA_VPT]; unsigned int rk[PA_VPT];
    if (ne == PA_BATCH) {
        const int4* r4 = (const int4*)(rowi + base);
        const int4* c4 = (const int4*)(coli + base);
#pragma unroll
        for (int jj = 0; jj < 4; ++jj) {
            int4 rv = r4[jj * 256 + t];
            int4 cv = c4[jj * 256 + t];
            int rr[4] = {rv.x, rv.y, rv.z, rv.w};
            int cc[4] = {cv.x, cv.y, cv.z, cv.w};
#pragma unroll
            for (int q = 0; q < 4; ++q) {
                int j = jj * 4 + q;
                unsigned int b = (unsigned int)rr[q] >> 8;
                pk[j] = ((unsigned int)(rr[q] & (BROWS - 1)) << 17) | (unsigned int)cc[q];
                bk[j] = b;
                rk[j] = atomicAdd(&hist[b], 1u);
            }
        }
    } else {
#pragma unroll
        for (int j = 0; j < PA_VPT; ++j) {
            int idx = j * 256 + t;
            if (idx < ne) {
                int r = rowi[base + idx];
                int c = coli[base + idx];
                unsigned int b = (unsigned int)r >> 8;
                pk[j] = ((unsigned int)(r & (BROWS - 1)) << 17) | (unsigned int)c;
                bk[j] = b;
                rk[j] = atomicAdd(&hist[b], 1u);
            } else bk[j] = 0xFFFFFFFFu;
        }
    }
    __syncthreads();

    sA[t] = hist[t]; sA[t + 256] = hist[t + 256];
    __syncthreads();
    unsigned int* src = sA; unsigned int* dst = sB;
    for (int off = 1; off < 512; off <<= 1) {
        unsigned int v0 = src[t] + ((t >= off) ? src[t - off] : 0u);
        unsigned int v1 = src[t + 256] + src[t + 256 - off];
        dst[t] = v0; dst[t + 256] = v1;
        __syncthreads();
        unsigned int* tmp = src; src = dst; dst = tmp;
    }

#pragma unroll
    for (int j = 0; j < PA_VPT; ++j) {
        if ((ne == PA_BATCH) || (bk[j] != 0xFFFFFFFFu)) {
            unsigned int b = bk[j];
            unsigned int slot = src[b] - hist[b] + rk[j];
            reorder[slot] = pk[j];
            bid[slot] = (unsigned short)b;
        }
    }
    __syncthreads();

    for (int s = t; s < ne; s += 256) {
        unsigned int b = bid[s];
        unsigned int off = src[b] - hist[b];
        pairs[gb[b] + ((unsigned int)s - off)] = reorder[s];
    }
}

// ---- pass 4a: per-bucket counting → rowloc/isq/bpref --------------------
__global__ __launch_bounds__(512) void k_count(const unsigned int* __restrict__ pairs,
                                               const unsigned int* __restrict__ btot,
                                               unsigned int* __restrict__ bpref_g,
                                               unsigned int* __restrict__ rowloc,
                                               float* __restrict__ isq, int n, int nbkt) {
    __shared__ unsigned int bsc[512];
    __shared__ unsigned int rcnt[256];
    __shared__ unsigned int ssc[256];
    int t = threadIdx.x;
    int b = blockIdx.x;
    int r0 = b * 256;

    bsc[t] = (t < nbkt) ? btot[t] : 0u;
    __syncthreads();
    for (int off = 1; off < 512; off <<= 1) {
        unsigned int u = (t >= off) ? bsc[t - off] : 0u;
        __syncthreads();
        bsc[t] += u;
        __syncthreads();
    }
    unsigned int bp = (b > 0) ? bsc[b - 1] : 0u;
    unsigned int cnt = btot[b];
    if (t == 0) bpref_g[b] = bp;
    if (cnt > A2_CAP) cnt = A2_CAP;

    if (t < 256) rcnt[t] = 0u;
    __syncthreads();
    {
        unsigned int nv4 = cnt >> 2;
        const u32x4* p4 = (const u32x4*)(pairs + bp);
        for (unsigned int i = t; i < nv4; i += 512) {
            u32x4 v = p4[i];
            atomicAdd(&rcnt[v[0] >> 17], 1u);
            atomicAdd(&rcnt[v[1] >> 17], 1u);
            atomicAdd(&rcnt[v[2] >> 17], 1u);
            atomicAdd(&rcnt[v[3] >> 17], 1u);
        }
        for (unsigned int i = (nv4 << 2) + t; i < cnt; i += 512)
            atomicAdd(&rcnt[pairs[bp + i] >> 17], 1u);
    }
    __syncthreads();
    unsigned int d = 0;
    if (t < 256) { d = rcnt[t]; ssc[t] = d; }
    __syncthreads();
    for (int off = 1; off < 256; off <<= 1) {
        unsigned int u = 0;
        if (t < 256 && t >= off) u = ssc[t - off];
        __syncthreads();
        if (t < 256) ssc[t] += u;
        __syncthreads();
    }
    if (t < 256 && r0 + t < n) {
        rowloc[r0 + t] = ssc[t] - d;
        isq[r0 + t] = rsqrtf((float)(d + 1u));
    }
}

// ---- layer 1 GEMM via MFMA: h1h = fp16(isq * (x @ W1)) ------------------
__global__ __launch_bounds__(256) void k_gemm1(const float* __restrict__ x,
                                               const float* __restrict__ W1,
                                               const float* __restrict__ isq,
                                               _Float16* __restrict__ h1h,
                                               int n, int ntile, int tstride) {
    int wave = threadIdx.x >> 6;
    int lane = threadIdx.x & 63;
    int g = lane >> 4;
    int m = lane & 15;

    bf16x8 wf[16];
#pragma unroll
    for (int s = 0; s < 16; ++s) {
#pragma unroll
        for (int j = 0; j < 8; ++j) {
            int k = s * 32 + g * 8 + j;
            wf[s][j] = bf16_rne(W1[k * H1F + m]);
        }
    }

    for (int tile = blockIdx.x * 4 + wave; tile < ntile; tile += tstride) {
        long r0 = (long)tile * 16;
        const float* xrow = x + (r0 + m) * DF;
        f32x4 acc = {0.0f, 0.0f, 0.0f, 0.0f};
#pragma unroll
        for (int s = 0; s < 16; ++s) {
            const float4* p = (const float4*)(xrow + s * 32 + g * 8);
            float4 a0 = p[0];
            float4 a1 = p[1];
            u32x4 aw;
            aw[0] = cvt_pk_bf16(a0.x, a0.y);
            aw[1] = cvt_pk_bf16(a0.z, a0.w);
            aw[2] = cvt_pk_bf16(a1.x, a1.y);
            aw[3] = cvt_pk_bf16(a1.z, a1.w);
            bf16x8 af = __builtin_bit_cast(bf16x8, aw);
            acc = __builtin_amdgcn_mfma_f32_16x16x32_bf16(af, wf[s], acc, 0, 0, 0);
        }
#pragma unroll
        for (int j = 0; j < 4; ++j) {
            long rr = r0 + g * 4 + j;
            h1h[rr * H1F + m] = (_Float16)(isq[rr] * acc[j]);
        }
    }
}

// ---- pass 4b FUSED: per-bucket counting sort (LDS CSR) + gather1 --------
// 1024 threads: sort phase strides the bucket; gather phase = 256 rows x 4.
// r1h = fp16(isq * relu(isq*(h1s[r]+Σ h1s[col]) + b1))
__global__ __launch_bounds__(1024) void k_sortg1(const unsigned int* __restrict__ pairs,
                                                 const unsigned int* __restrict__ btot,
                                                 const unsigned int* __restrict__ bpref_g,
                                                 const unsigned int* __restrict__ rowloc,
                                                 const float* __restrict__ isq,
                                                 const _Float16* __restrict__ h1h,
                                                 const float* __restrict__ b1,
                                                 _Float16* __restrict__ r1h, int n) {
    __shared__ unsigned int sorted[A2_CAP];   // 40 KB
    __shared__ unsigned int rloc[256];
    __shared__ unsigned int rcur[256];
    int t = threadIdx.x;
    int b = blockIdx.x;
    int r0 = b * 256;
    unsigned int bp = bpref_g[b];
    unsigned int cnt = btot[b];
    if (cnt > A2_CAP) cnt = A2_CAP;

    if (t < 256) {
        rloc[t] = (r0 + t < n) ? rowloc[r0 + t] : 0u;
        rcur[t] = 0u;
    }
    __syncthreads();
    {
        unsigned int nv4 = cnt >> 2;
        const u32x4* p4 = (const u32x4*)(pairs + bp);
        for (unsigned int i = t; i < nv4; i += 1024) {
            u32x4 v = p4[i];
#pragma unroll
            for (int q = 0; q < 4; ++q) {
                unsigned int lr = v[q] >> 17;
                unsigned int rk = atomicAdd(&rcur[lr], 1u);
                sorted[rloc[lr] + rk] = v[q] & 0x1FFFFu;
            }
        }
        for (unsigned int i = (nv4 << 2) + t; i < cnt; i += 1024) {
            unsigned int p = pairs[bp + i];
            unsigned int lr = p >> 17;
            unsigned int rk = atomicAdd(&rcur[lr], 1u);
            sorted[rloc[lr] + rk] = p & 0x1FFFFu;
        }
    }
    __syncthreads();

    // ---- gather1 phase: 4 lanes/row, CSR from LDS, 4-deep MLP ----
    int lr = t >> 2;
    int r = r0 + lr;
    if (r >= n) return;
    int hf = t & 1, sg = (t >> 1) & 1;
    unsigned int start = rloc[lr];
    unsigned int cntr = rcur[lr];     // row degree, free from the sort
    float s = isq[r];
    const half8* hb = (const half8*)h1h;
    float acc[8];
    if (sg == 0) {
        half8 me = hb[(size_t)r * 2 + hf];
#pragma unroll
        for (int i = 0; i < 8; ++i) acc[i] = (float)me[i];   // self-loop term
    } else {
#pragma unroll
        for (int i = 0; i < 8; ++i) acc[i] = 0.0f;
    }
    unsigned int k = sg;
    for (; k + 6 < cntr; k += 8) {
        unsigned int c0 = sorted[start + k];
        unsigned int c1 = sorted[start + k + 2];
        unsigned int c2 = sorted[start + k + 4];
        unsigned int c3 = sorted[start + k + 6];
        half8 v0 = hb[(size_t)c0 * 2 + hf];
        half8 v1 = hb[(size_t)c1 * 2 + hf];
        half8 v2 = hb[(size_t)c2 * 2 + hf];
        half8 v3 = hb[(size_t)c3 * 2 + hf];
#pragma unroll
        for (int i = 0; i < 8; ++i)
            acc[i] += ((float)v0[i] + (float)v1[i]) + ((float)v2[i] + (float)v3[i]);
    }
    for (; k < cntr; k += 2) {
        unsigned int c0 = sorted[start + k];
        half8 v0 = hb[(size_t)c0 * 2 + hf];
#pragma unroll
        for (int i = 0; i < 8; ++i) acc[i] += (float)v0[i];
    }
#pragma unroll
    for (int i = 0; i < 8; ++i) acc[i] += __shfl_xor(acc[i], 2);
    if (sg == 0) {
        const float* b1p = b1 + hf * 8;
        half8 o;
#pragma unroll
        for (int i = 0; i < 8; ++i)
            o[i] = (_Float16)(s * fmaxf(fmaf(s, acc[i], b1p[i]), 0.0f));
        ((half8*)r1h)[(size_t)r * 2 + hf] = o;
    }
}

// ---- pass 4c FUSED: per-bucket counting sort (LDS CSR) + gather2
//                     + @W2 + b2 + log_softmax ----------------------------
__global__ __launch_bounds__(1024) void k_sortg2(const unsigned int* __restrict__ pairs,
                                                 const unsigned int* __restrict__ btot,
                                                 const unsigned int* __restrict__ bpref_g,
                                                 const unsigned int* __restrict__ rowloc,
                                                 const float* __restrict__ isq,
                                                 const _Float16* __restrict__ r1h,
                                                 const float* __restrict__ W2,
                                                 const float* __restrict__ b2,
                                                 float* __restrict__ out, int n) {
    __shared__ unsigned int sorted[A2_CAP];   // 40 KB
    __shared__ unsigned int rloc[256];
    __shared__ unsigned int rcur[256];
    int t = threadIdx.x;
    int b = blockIdx.x;
    int r0 = b * 256;
    unsigned int bp = bpref_g[b];
    unsigned int cnt = btot[b];
    if (cnt > A2_CAP) cnt = A2_CAP;

    if (t < 256) {
        rloc[t] = (r0 + t < n) ? rowloc[r0 + t] : 0u;
        rcur[t] = 0u;
    }
    __syncthreads();
    {
        unsigned int nv4 = cnt >> 2;
        const u32x4* p4 = (const u32x4*)(pairs + bp);
        for (unsigned int i = t; i < nv4; i += 1024) {
            u32x4 v = p4[i];
#pragma unroll
            for (int q = 0; q < 4; ++q) {
                unsigned int lr = v[q] >> 17;
                unsigned int rk = atomicAdd(&rcur[lr], 1u);
                sorted[rloc[lr] + rk] = v[q] & 0x1FFFFu;
            }
        }
        for (unsigned int i = (nv4 << 2) + t; i < cnt; i += 1024) {
            unsigned int p = pairs[bp + i];
            unsigned int lr = p >> 17;
            unsigned int rk = atomicAdd(&rcur[lr], 1u);
            sorted[rloc[lr] + rk] = p & 0x1FFFFu;
        }
    }
    __syncthreads();

    // ---- gather2 phase: 4 lanes/row, CSR from LDS, 4-deep MLP ----
    int lr = t >> 2;
    int r = r0 + lr;
    if (r >= n) return;
    int hf = t & 1, sg = (t >> 1) & 1;
    unsigned int start = rloc[lr];
    unsigned int cntr = rcur[lr];
    float s = isq[r];
    const half8* hb = (const half8*)r1h;
    float acc[8];
    if (sg == 0) {
        half8 me = hb[(size_t)r * 2 + hf];
#pragma unroll
        for (int i = 0; i < 8; ++i) acc[i] = (float)me[i];   // self-loop term
    } else {
#pragma unroll
        for (int i = 0; i < 8; ++i) acc[i] = 0.0f;
    }
    unsigned int k = sg;
    for (; k + 6 < cntr; k += 8) {
        unsigned int c0 = sorted[start + k];
        unsigned int c1 = sorted[start + k + 2];
        unsigned int c2 = sorted[start + k + 4];
        unsigned int c3 = sorted[start + k + 6];
        half8 v0 = hb[(size_t)c0 * 2 + hf];
        half8 v1 = hb[(size_t)c1 * 2 + hf];
        half8 v2 = hb[(size_t)c2 * 2 + hf];
        half8 v3 = hb[(size_t)c3 * 2 + hf];
#pragma unroll
        for (int i = 0; i < 8; ++i)
            acc[i] += ((float)v0[i] + (float)v1[i]) + ((float)v2[i] + (float)v3[i]);
    }
    for (; k < cntr; k += 2) {
        unsigned int c0 = sorted[start + k];
        half8 v0 = hb[(size_t)c0 * 2 + hf];
#pragma unroll
        for (int i = 0; i < 8; ++i) acc[i] += (float)v0[i];
    }
#pragma unroll
    for (int i = 0; i < 8; ++i) acc[i] += __shfl_xor(acc[i], 2);
    int f0 = hf * 8;
    float o0 = 0.0f, o1 = 0.0f;
#pragma unroll
    for (int i = 0; i < 8; ++i) {
        o0 = fmaf(acc[i], W2[(f0 + i) * 2 + 0], o0);
        o1 = fmaf(acc[i], W2[(f0 + i) * 2 + 1], o1);
    }
    o0 += __shfl_xor(o0, 1);
    o1 += __shfl_xor(o1, 1);
    if ((t & 3) == 0) {
        float a = fmaf(s, o0, b2[0]);
        float bb = fmaf(s, o1, b2[1]);
        float m = fmaxf(a, bb);
        float lse = m + logf(expf(a - m) + expf(bb - m));
        out[(size_t)r * 2 + 0] = a - lse;
        out[(size_t)r * 2 + 1] = bb - lse;
    }
}

extern "C" void kernel_launch(void* const* d_in, const int* in_sizes, int n_in,
                              void* d_out, int out_size, void* d_ws, size_t ws_size,
                              hipStream_t stream) {
    const float* x  = (const float*)d_in[0];
    const int*   ei = (const int*)d_in[1];
    const float* W1 = (const float*)d_in[2];
    const float* b1 = (const float*)d_in[3];
    const float* W2 = (const float*)d_in[4];
    const float* b2 = (const float*)d_in[5];

    int n = in_sizes[0] / DF;   // 100000
    int E = in_sizes[1] / 2;    // 3200000
    const int* rowi = ei;
    const int* coli = ei + E;

    int NBKT = (n + BROWS - 1) / BROWS;          // 391
    int NBLK = (E + PA_BATCH - 1) / PA_BATCH;    // 782
    int NBLKP = NBLK + 2;                        // padded leading dim

    char* base = (char*)d_ws;
    float*        isq    = (float*)base;        base += (size_t)n * 4;
    unsigned int* rowloc = (unsigned int*)base; base += (size_t)n * 4;
    unsigned int* btot   = (unsigned int*)base; base += 512 * 4;
    unsigned int* bpref  = (unsigned int*)base; base += 512 * 4;
    unsigned int* ghist  = (unsigned int*)base; base += (size_t)NBKT * NBLKP * 4;
    unsigned int* gbase  = (unsigned int*)base; base += (size_t)NBKT * NBLKP * 4;
    _Float16*     h1h    = (_Float16*)base;     base += (size_t)n * H1F * 2;
    _Float16*     r1h    = (_Float16*)base;     base += (size_t)n * H1F * 2;
    unsigned int* pairs  = (unsigned int*)base; base += (size_t)E * 4;
    float*        out    = (float*)d_out;

    k_hist<<<NBLK, 256, 0, stream>>>(rowi, ghist, E, NBKT, NBLKP);
    k_colscan<<<NBKT, 256, 0, stream>>>(ghist, gbase, btot, NBLK, NBLKP);
    k_scatter<<<NBLK, 256, 0, stream>>>(rowi, coli, gbase, btot, pairs, E, NBKT, NBLKP);
    k_count<<<NBKT, 512, 0, stream>>>(pairs, btot, bpref, rowloc, isq, n, NBKT);
    {
        int ntile = (n + 15) / 16;                 // 6250
        int ngrid = 782;                           // ~2 tiles per wave
        k_gemm1<<<ngrid, 256, 0, stream>>>(x, W1, isq, h1h, n, ntile, ngrid * 4);
    }
    k_sortg1<<<NBKT, 1024, 0, stream>>>(pairs, btot, bpref, rowloc, isq, h1h, b1, r1h, n);
    k_sortg2<<<NBKT, 1024, 0, stream>>>(pairs, btot, bpref, rowloc, isq, r1h, W2, b2, out, n);
}